// Round 9
// baseline (424.118 us; speedup 1.0000x reference)
//
#include <hip/hip_runtime.h>
#include <math.h>

#define B_ 128
#define N_ 100
#define E_ 100
#define D_ 64
#define EH 25
#define LALPHA 0.2f
#define NEGV -9e15f

typedef __attribute__((ext_vector_type(8))) short short8;
typedef __attribute__((ext_vector_type(4))) short short4v;
typedef __attribute__((ext_vector_type(4))) float f32x4;

__device__ __forceinline__ float4 ld4(const float* p) { return *reinterpret_cast<const float4*>(p); }

__device__ __forceinline__ unsigned short f2bf(float x) {
    union { float f; unsigned u; } c; c.f = x;
    return (unsigned short)((c.u + 0x7FFF + ((c.u >> 16) & 1)) >> 16);
}
__device__ __forceinline__ float bf2f(unsigned short h) {
    union { unsigned u; float f; } c; c.u = (unsigned)h << 16;
    return c.f;
}

#define MFMA(a, b, c) __builtin_amdgcn_mfma_f32_16x16x32_bf16((a), (b), (c), 0, 0, 0)

// One block per (quarter q, batch b). Both layers, n2e+e2n fused.
// Inter-block (4 siblings of b) sync via monotonic device counter in ws.
__global__ __launch_bounds__(512, 4) void k_fused(
    const float* __restrict__ hidden, const float* __restrict__ Hm,
    const float* __restrict__ s_c,
    const float* __restrict__ a10, const float* __restrict__ a11, const float* __restrict__ a12,
    const float* __restrict__ a20, const float* __restrict__ a21, const float* __restrict__ a22,
    float* __restrict__ edge, float* __restrict__ hnext, float* __restrict__ out,
    int* __restrict__ cnt)
{
    __shared__ __align__(16) unsigned short hh[112 * 72];   // h/hnext/edge bf16 [row][d]; PT alias rows 0-31 (stride 136)
    __shared__ __align__(16) unsigned short hT[64 * 136];   // transposed bf16 [d][row]; cols 100-135 zero
    __shared__ __align__(16) unsigned short m01[32 * 136];  // n2e mask bf16 [e_loc][n] (persists both layers)
    __shared__ __align__(16) float S[25 * 112];             // scores [row_loc][col]
    __shared__ __align__(16) float ec[32 * 66];             // ec (n2e) / ht (e2n) f32
    __shared__ unsigned char kkA[112 * 32];                 // [n][e_loc]
    __shared__ unsigned char kkB[112 * 32];                 // [e][n_loc]
    __shared__ __align__(16) float a_lds[6 * 68];           // a10,a11,a12,a20,a21,a22

    const int b = blockIdx.y, q = blockIdx.x;
    const int e_base = q * EH, n_base = q * EH;
    const int tid = threadIdx.x;
    const int wv = tid >> 6, ln = tid & 63, l15 = ln & 15, l4 = ln >> 4;

    // ---- helpers ----
    auto stage_rows = [&](const float* src) {   // src: [100][64] f32 -> hh bf16 + hT transposed
        for (int g = tid; g < 1600; g += 512) {
            const int r = g >> 4, d0 = (g & 15) * 4;
            const float4 v = ld4(&src[r * 64 + d0]);
            const unsigned short q0 = f2bf(v.x), q1 = f2bf(v.y), q2 = f2bf(v.z), q3 = f2bf(v.w);
            short4v p = { (short)q0, (short)q1, (short)q2, (short)q3 };
            *reinterpret_cast<short4v*>(&hh[r * 72 + d0]) = p;
            hT[(d0 + 0) * 136 + r] = q0; hT[(d0 + 1) * 136 + r] = q1;
            hT[(d0 + 2) * 136 + r] = q2; hT[(d0 + 3) * 136 + r] = q3;
        }
    };
    auto prefill_S = [&]() {
        for (int i = tid; i < 2800; i += 512) S[i] = NEGV;
    };
    auto sync4 = [&](int target) {
        __threadfence();
        __syncthreads();
        if (tid == 0) {
            atomicAdd(&cnt[b], 1);
            while (__hip_atomic_load(&cnt[b], __ATOMIC_RELAXED, __HIP_MEMORY_SCOPE_AGENT) < target)
                __builtin_amdgcn_s_sleep(4);
            __threadfence();
        }
        __syncthreads();
    };
    // score phase: S[row][col] = leaky( (ec_row * a_k) . hh_col ), predicated on mask==k+1.
    auto score_phase = [&](const unsigned char* kkX, int a_row0) {
        if (wv < 6) {
            const int Mt = wv & 1, k = wv >> 1;
            const int arow = Mt * 16 + l15;
            f32x4 acc[7];
            #pragma unroll
            for (int j = 0; j < 7; ++j) { f32x4 z = { 0,0,0,0 }; acc[j] = z; }
            #pragma unroll
            for (int ks = 0; ks < 2; ++ks) {
                const int ko = ks * 32 + l4 * 8;
                short8 ah, al;
                #pragma unroll
                for (int jj = 0; jj < 8; ++jj) {
                    const float w = ec[arow * 66 + ko + jj] * a_lds[(a_row0 + k) * 68 + ko + jj];
                    const unsigned short hi = f2bf(w);
                    ah[jj] = (short)hi;
                    al[jj] = (short)f2bf(w - bf2f(hi));
                }
                #pragma unroll
                for (int j = 0; j < 7; ++j) {
                    const short8 bf = *reinterpret_cast<const short8*>(&hh[(j * 16 + l15) * 72 + ko]);
                    acc[j] = MFMA(ah, bf, acc[j]);
                    acc[j] = MFMA(al, bf, acc[j]);
                }
            }
            #pragma unroll
            for (int j = 0; j < 7; ++j) {
                const int col = j * 16 + l15;
                const int r0 = Mt * 16 + l4 * 4;
                const unsigned kw = *reinterpret_cast<const unsigned*>(&kkX[col * 32 + r0]);
                #pragma unroll
                for (int r = 0; r < 4; ++r) {
                    const int kv = (kw >> (8 * r)) & 255;
                    if (kv == k + 1) {
                        float v = acc[j][r];
                        v = (v >= 0.f) ? v : LALPHA * v;
                        S[(r0 + r) * 112 + col] = v;  // r0+r < 25 guaranteed: mask pad rows are 0
                    }
                }
            }
        }
    };
    auto softmax_phase = [&]() {   // S rows 0..24 (len 100) -> PT bf16 (alias hh, stride 136), pads 0
        unsigned short* PT = hh;
        const int c1 = ln, c2 = ln + 64;
        #pragma unroll
        for (int t = 0; t < 4; ++t) {
            const int r = wv + 8 * t;
            if (r < EH) {
                const float s1 = S[r * 112 + c1];
                const float s2 = (c2 < 100) ? S[r * 112 + c2] : -INFINITY;
                float mx = fmaxf(s1, s2);
                #pragma unroll
                for (int off = 32; off; off >>= 1) mx = fmaxf(mx, __shfl_xor(mx, off));
                const float p1 = __expf(s1 - mx);
                const float p2 = (c2 < 100) ? __expf(s2 - mx) : 0.f;
                float sum = p1 + p2;
                #pragma unroll
                for (int off = 32; off; off >>= 1) sum += __shfl_xor(sum, off);
                const float inv = 1.f / sum;
                PT[r * 136 + c1] = f2bf(p1 * inv);
                PT[r * 136 + c2] = (c2 < 100) ? f2bf(p2 * inv) : (unsigned short)0;
            }
        }
    };

    // ---- L1 staging ----
    stage_rows(&hidden[(size_t)b * N_ * D_]);
    for (int i = tid; i < 1536; i += 512) { const int r = 100 + (i >> 7), d = i & 127; if (d < 72) hh[r * 72 + d] = 0; }
    for (int i = tid; i < 4096; i += 512) { const int d = i >> 6, c = i & 63; if (c < 36) hT[d * 136 + 100 + c] = 0; }
    for (int i = tid; i < 544; i += 512) { short8 z = { 0,0,0,0,0,0,0,0 }; reinterpret_cast<short8*>(m01)[i] = z; }
    if (tid < 384) {
        const int k = tid >> 6, d = tid & 63;
        const float* ap = (k == 0) ? a10 : (k == 1) ? a11 : (k == 2) ? a12 : (k == 3) ? a20 : (k == 4) ? a21 : a22;
        a_lds[k * 68 + d] = ap[d];
    }
    __syncthreads();
    for (int i = tid; i < 3584; i += 512) {       // kkA + m01
        const int n = i >> 5, le = i & 31;
        int v = 0;
        if (n < 100 && le < EH) v = (int)Hm[((size_t)b * N_ + n) * E_ + e_base + le];
        kkA[n * 32 + le] = (unsigned char)v;
        if (v > 0) m01[le * 136 + n] = 0x3F80;
    }
    for (int i = tid; i < 3584; i += 512) {       // kkB
        const int e = i >> 5, lnn = i & 31;
        int v = 0;
        if (e < 100 && lnn < EH) v = (int)Hm[((size_t)b * N_ + n_base + lnn) * E_ + e];
        kkB[e * 32 + lnn] = (unsigned char)v;
    }
    prefill_S();
    __syncthreads();

    f32x4 racc = { 0,0,0,0 };
    for (int layer = 0; layer < 2; ++layer) {
        const float* hsrc = layer ? hnext : hidden;
        if (layer == 1) {
            stage_rows(&hnext[(size_t)b * N_ * D_]);
            prefill_S();
            __syncthreads();
        }
        // ---- n2e: B (ec = m01 . h) ----
        {
            const int Mt = wv >> 2, Nt = wv & 3;
            f32x4 acc = { 0,0,0,0 };
            #pragma unroll
            for (int ks = 0; ks < 4; ++ks) {
                const int ko = ks * 32 + l4 * 8;
                const short8 af = *reinterpret_cast<const short8*>(&m01[(Mt * 16 + l15) * 136 + ko]);
                const short8 bf = *reinterpret_cast<const short8*>(&hT[(Nt * 16 + l15) * 136 + ko]);
                acc = MFMA(af, bf, acc);
            }
            #pragma unroll
            for (int r = 0; r < 4; ++r)
                ec[(Mt * 16 + l4 * 4 + r) * 66 + Nt * 16 + l15] = acc[r];
        }
        __syncthreads();
        score_phase(kkA, 0);
        __syncthreads();
        softmax_phase();
        __syncthreads();
        // ---- n2e: E (edge quarter = PT . hT) ----
        {
            const unsigned short* PT = hh;
            const int Mt = wv >> 2, Nt = wv & 3;
            f32x4 acc = { 0,0,0,0 };
            #pragma unroll
            for (int ks = 0; ks < 4; ++ks) {
                const int ko = ks * 32 + l4 * 8;
                const short8 af = *reinterpret_cast<const short8*>(&PT[(Mt * 16 + l15) * 136 + ko]);
                const short8 bf = *reinterpret_cast<const short8*>(&hT[(Nt * 16 + l15) * 136 + ko]);
                acc = MFMA(af, bf, acc);
            }
            #pragma unroll
            for (int r = 0; r < 4; ++r) {
                const int e = Mt * 16 + l4 * 4 + r;
                if (e < EH) edge[((size_t)b * E_ + e_base + e) * D_ + Nt * 16 + l15] = acc[r];
            }
        }
        sync4(layer * 8 + 4);

        // ---- e2n staging: hh/hT <- edge (full), ec <- ht = h + s_c (quarter) ----
        stage_rows(&edge[(size_t)b * E_ * D_]);
        for (int g = tid; g < 400; g += 512) {
            const int lnn = g >> 4, d0 = (g & 15) * 4;
            const float4 hv = ld4(&hsrc[((size_t)b * N_ + n_base + lnn) * D_ + d0]);
            const float4 sc = ld4(&s_c[(size_t)b * D_ + d0]);
            ec[lnn * 66 + d0 + 0] = hv.x + sc.x;
            ec[lnn * 66 + d0 + 1] = hv.y + sc.y;
            ec[lnn * 66 + d0 + 2] = hv.z + sc.z;
            ec[lnn * 66 + d0 + 3] = hv.w + sc.w;
        }
        prefill_S();
        __syncthreads();
        score_phase(kkB, 3);
        __syncthreads();
        softmax_phase();
        __syncthreads();
        // ---- e2n: Out (r = P2T . edgeT) ----
        {
            const unsigned short* P2T = hh;
            const int Mt = wv >> 2, Nt = wv & 3;
            f32x4 acc = { 0,0,0,0 };
            #pragma unroll
            for (int ks = 0; ks < 4; ++ks) {
                const int ko = ks * 32 + l4 * 8;
                const short8 af = *reinterpret_cast<const short8*>(&P2T[(Mt * 16 + l15) * 136 + ko]);
                const short8 bf = *reinterpret_cast<const short8*>(&hT[(Nt * 16 + l15) * 136 + ko]);
                acc = MFMA(af, bf, acc);
            }
            if (layer == 0) {
                #pragma unroll
                for (int r = 0; r < 4; ++r) {
                    const int nr = Mt * 16 + l4 * 4 + r;
                    if (nr < EH)
                        hnext[((size_t)b * N_ + n_base + nr) * D_ + Nt * 16 + l15] = acc[r];
                }
                racc = acc;
            } else {
                #pragma unroll
                for (int r = 0; r < 4; ++r) {
                    const int nr = Mt * 16 + l4 * 4 + r;
                    if (nr < EH)
                        out[((size_t)b * N_ + n_base + nr) * D_ + Nt * 16 + l15] = racc[r] + acc[r];
                }
            }
        }
        if (layer == 0) sync4(8);
    }
}

extern "C" void kernel_launch(void* const* d_in, const int* in_sizes, int n_in,
                              void* d_out, int out_size, void* d_ws, size_t ws_size,
                              hipStream_t stream) {
    const float* hidden = (const float*)d_in[0];
    const float* Hm     = (const float*)d_in[1];
    const float* s_c    = (const float*)d_in[2];
    const float* a10    = (const float*)d_in[3];
    const float* a11    = (const float*)d_in[4];
    const float* a12    = (const float*)d_in[5];
    const float* a20    = (const float*)d_in[6];
    const float* a21    = (const float*)d_in[7];
    const float* a22    = (const float*)d_in[8];
    float* out = (float*)d_out;

    float* edge  = (float*)d_ws;                          // B*E*D f32
    float* hnext = edge + (size_t)B_ * E_ * D_;           // B*N*D f32
    int*   cnt   = (int*)(hnext + (size_t)B_ * N_ * D_);  // B_ ints

    hipMemsetAsync(cnt, 0, B_ * sizeof(int), stream);
    k_fused<<<dim3(4, B_), 512, 0, stream>>>(hidden, Hm, s_c,
                                             a10, a11, a12, a20, a21, a22,
                                             edge, hnext, out, cnt);
}

// Round 10
// 159.156 us; speedup vs baseline: 2.6648x; 2.6648x over previous
//
#include <hip/hip_runtime.h>
#include <math.h>

#define B_ 128
#define N_ 100
#define E_ 100
#define D_ 64
#define LALPHA 0.2f
#define NEGV -9e15f

typedef __attribute__((ext_vector_type(8))) short short8;
typedef __attribute__((ext_vector_type(4))) short short4v;
typedef __attribute__((ext_vector_type(4))) float f32x4;

__device__ __forceinline__ float4 ld4(const float* p) { return *reinterpret_cast<const float4*>(p); }

__device__ __forceinline__ unsigned short f2bf(float x) {
    union { float f; unsigned u; } c; c.f = x;
    return (unsigned short)((c.u + 0x7FFF + ((c.u >> 16) & 1)) >> 16);
}
__device__ __forceinline__ float bf2f(unsigned short h) {
    union { unsigned u; float f; } c; c.u = (unsigned)h << 16;
    return c.f;
}

#define MFMA(a, b, c) __builtin_amdgcn_mfma_f32_16x16x32_bf16((a), (b), (c), 0, 0, 0)

// One block per batch b. 1024 threads (16 waves). Both layers fully in-LDS;
// edge/hnext never round-trip through global except r1 -> out (reused as L2 input).
__global__ __launch_bounds__(1024, 4) void k_mono(
    const float* __restrict__ hidden, const float* __restrict__ Hm,
    const float* __restrict__ s_c,
    const float* __restrict__ a10, const float* __restrict__ a11, const float* __restrict__ a12,
    const float* __restrict__ a20, const float* __restrict__ a21, const float* __restrict__ a22,
    float* __restrict__ out)
{
    __shared__ __align__(16) unsigned short hh[112 * 72];    // h / edge / r1, bf16 [row][d]
    __shared__ __align__(16) unsigned short hT[64 * 136];    // transposed [d][row]; cols 100-135 zero
    __shared__ __align__(16) unsigned short m01[112 * 136];  // mask bf16 [e][n]; PT alias after softmax
    __shared__ __align__(16) float S[100 * 104];             // scores [row][col]
    __shared__ __align__(16) float ec[112 * 66];             // ec (n2e) / ht (e2n) f32 [row][d]
    __shared__ __align__(16) unsigned char kkA[112 * 104 + 16]; // H k-values [n][e]
    __shared__ __align__(16) float a_lds[6 * 68];
    __shared__ __align__(16) float sc_lds[64];

    const int b = blockIdx.x;
    const int tid = threadIdx.x;
    const int wv = tid >> 6, ln = tid & 63, l15 = ln & 15, l4 = ln >> 4;

    // ================= initial staging =================
    for (int g = tid; g < 1600; g += 1024) {
        const int r = g >> 4, d0 = (g & 15) * 4;
        const float4 v = ld4(&hidden[((size_t)b * N_ + r) * D_ + d0]);
        const unsigned short q0 = f2bf(v.x), q1 = f2bf(v.y), q2 = f2bf(v.z), q3 = f2bf(v.w);
        short4v p = { (short)q0, (short)q1, (short)q2, (short)q3 };
        *reinterpret_cast<short4v*>(&hh[r * 72 + d0]) = p;
        hT[(d0 + 0) * 136 + r] = q0; hT[(d0 + 1) * 136 + r] = q1;
        hT[(d0 + 2) * 136 + r] = q2; hT[(d0 + 3) * 136 + r] = q3;
    }
    for (int i = tid; i < 864; i += 1024) {          // hh rows 100-111 = 0
        const int r = 100 + i / 72, d = i % 72;
        hh[r * 72 + d] = 0;
    }
    for (int i = tid; i < 2304; i += 1024) {         // hT cols 100-135 = 0
        const int d = i / 36, c = 100 + i % 36;
        hT[d * 136 + c] = 0;
    }
    for (int i = tid; i < 10000; i += 1024) {        // kkA
        const int n = i / 100, e = i % 100;
        kkA[n * 104 + e] = (unsigned char)(int)Hm[((size_t)b * N_ + n) * E_ + e];
    }
    if (tid < 384) {
        const int k = tid >> 6, d = tid & 63;
        const float* ap = (k == 0) ? a10 : (k == 1) ? a11 : (k == 2) ? a12
                        : (k == 3) ? a20 : (k == 4) ? a21 : a22;
        a_lds[k * 68 + d] = ap[d];
    }
    if (tid < 64) sc_lds[tid] = s_c[(size_t)b * D_ + tid];
    __syncthreads();

    // ================= helpers =================
    auto prefill_S = [&]() {
        for (int i = tid; i < 10400; i += 1024) S[i] = NEGV;
    };
    // C = A(m01-region rows M) . B(hT rows N), K=128. 28 jobs (Mt 0..6, Nt 0..3).
    auto mm_PT_hT = [&](f32x4& accA, f32x4& accB) {
        {
            const int Mt = wv >> 2, Nt = wv & 3;
            #pragma unroll
            for (int ks = 0; ks < 4; ++ks) {
                const int ko = ks * 32 + l4 * 8;
                const short8 af = *reinterpret_cast<const short8*>(&m01[(Mt * 16 + l15) * 136 + ko]);
                const short8 bf = *reinterpret_cast<const short8*>(&hT[(Nt * 16 + l15) * 136 + ko]);
                accA = MFMA(af, bf, accA);
            }
        }
        const int j = wv + 16;
        if (j < 28) {
            const int Mt = j >> 2, Nt = j & 3;
            #pragma unroll
            for (int ks = 0; ks < 4; ++ks) {
                const int ko = ks * 32 + l4 * 8;
                const short8 af = *reinterpret_cast<const short8*>(&m01[(Mt * 16 + l15) * 136 + ko]);
                const short8 bf = *reinterpret_cast<const short8*>(&hT[(Nt * 16 + l15) * 136 + ko]);
                accB = MFMA(af, bf, accB);
            }
        }
    };
    // score: S[row][col] = leaky((ec_row * a_k) . hh_col), predicated on k-match.
    auto score = [&](int arow0, bool trans) {
        for (int j = wv; j < 21; j += 16) {
            const int Mt = j / 3, k = j - Mt * 3;
            f32x4 acc[7];
            #pragma unroll
            for (int t = 0; t < 7; ++t) { f32x4 z = { 0, 0, 0, 0 }; acc[t] = z; }
            const int arow = Mt * 16 + l15;
            #pragma unroll
            for (int ks = 0; ks < 2; ++ks) {
                const int ko = ks * 32 + l4 * 8;
                short8 ah, al;
                #pragma unroll
                for (int jj = 0; jj < 8; ++jj) {
                    const float w = ec[arow * 66 + ko + jj] * a_lds[(arow0 + k) * 68 + ko + jj];
                    const unsigned short hi = f2bf(w);
                    ah[jj] = (short)hi;
                    al[jj] = (short)f2bf(w - bf2f(hi));
                }
                #pragma unroll
                for (int j2 = 0; j2 < 7; ++j2) {
                    const short8 bf = *reinterpret_cast<const short8*>(&hh[(j2 * 16 + l15) * 72 + ko]);
                    acc[j2] = MFMA(ah, bf, acc[j2]);
                    acc[j2] = MFMA(al, bf, acc[j2]);
                }
            }
            const int r0 = Mt * 16 + l4 * 4;
            #pragma unroll
            for (int j2 = 0; j2 < 7; ++j2) {
                const int col = j2 * 16 + l15;
                if (col < 100) {
                    if (!trans) {
                        const unsigned kw = *reinterpret_cast<const unsigned*>(&kkA[col * 104 + r0]);
                        #pragma unroll
                        for (int r = 0; r < 4; ++r) {
                            if (r0 + r < 100) {
                                const int kv = (kw >> (8 * r)) & 255;
                                if (kv == k + 1) {
                                    float v = acc[j2][r];
                                    v = (v >= 0.f) ? v : LALPHA * v;
                                    S[(r0 + r) * 104 + col] = v;
                                }
                            }
                        }
                    } else {
                        #pragma unroll
                        for (int r = 0; r < 4; ++r) {
                            if (r0 + r < 100) {
                                const int kv = kkA[(r0 + r) * 104 + col];
                                if (kv == k + 1) {
                                    float v = acc[j2][r];
                                    v = (v >= 0.f) ? v : LALPHA * v;
                                    S[(r0 + r) * 104 + col] = v;
                                }
                            }
                        }
                    }
                }
            }
        }
    };
    auto softmax_to_PT = [&]() {    // PT aliases m01
        #pragma unroll
        for (int t = 0; t < 7; ++t) {
            const int r = wv + 16 * t;
            if (r < 100) {
                const int c2 = ln + 64;
                const float s1 = S[r * 104 + ln];
                const float s2 = (c2 < 100) ? S[r * 104 + c2] : -INFINITY;
                float mx = fmaxf(s1, s2);
                #pragma unroll
                for (int off = 32; off; off >>= 1) mx = fmaxf(mx, __shfl_xor(mx, off));
                const float p1 = __expf(s1 - mx);
                const float p2 = (c2 < 100) ? __expf(s2 - mx) : 0.f;
                float sum = p1 + p2;
                #pragma unroll
                for (int off = 32; off; off >>= 1) sum += __shfl_xor(sum, off);
                const float inv = 1.f / sum;
                m01[r * 136 + ln] = f2bf(p1 * inv);
                m01[r * 136 + c2] = (c2 < 100) ? f2bf(p2 * inv) : (unsigned short)0;
            }
        }
    };

    // ================= layers =================
    for (int layer = 0; layer < 2; ++layer) {
        // zero m01 + prefill S (both free regions here)
        for (int i = tid; i < 1904; i += 1024) {
            short8 z = { 0, 0, 0, 0, 0, 0, 0, 0 };
            reinterpret_cast<short8*>(m01)[i] = z;
        }
        prefill_S();
        __syncthreads();
        // set m01 from kkA
        for (int i = tid; i < 10000; i += 1024) {
            const int n = i / 100, e = i % 100;
            if (kkA[n * 104 + e]) m01[e * 136 + n] = 0x3F80;
        }
        __syncthreads();
        // ec = m01 . h
        {
            f32x4 aA = { 0, 0, 0, 0 }, aB = { 0, 0, 0, 0 };
            mm_PT_hT(aA, aB);
            {
                const int Mt = wv >> 2, Nt = wv & 3;
                #pragma unroll
                for (int r = 0; r < 4; ++r)
                    ec[(Mt * 16 + l4 * 4 + r) * 66 + Nt * 16 + l15] = aA[r];
            }
            const int j = wv + 16;
            if (j < 28) {
                const int Mt = j >> 2, Nt = j & 3;
                #pragma unroll
                for (int r = 0; r < 4; ++r)
                    ec[(Mt * 16 + l4 * 4 + r) * 66 + Nt * 16 + l15] = aB[r];
            }
        }
        __syncthreads();
        score(0, false);            // S[e][n]
        __syncthreads();
        softmax_to_PT();            // PT[e][n]
        __syncthreads();
        // edge = PT . hT  (keep in regs)
        f32x4 eA = { 0, 0, 0, 0 }, eB = { 0, 0, 0, 0 };
        mm_PT_hT(eA, eB);
        __syncthreads();
        // restage: hh/hT <- bf16(edge); ec <- ht = h(+layer src) + s_c; prefill S
        {
            {
                const int Mt = wv >> 2, Nt = wv & 3;
                #pragma unroll
                for (int r = 0; r < 4; ++r) {
                    const int e = Mt * 16 + l4 * 4 + r;
                    if (e < 100) {
                        const unsigned short q = f2bf(eA[r]);
                        hh[e * 72 + Nt * 16 + l15] = q;
                        hT[(Nt * 16 + l15) * 136 + e] = q;
                    }
                }
            }
            const int j = wv + 16;
            if (j < 28) {
                const int Mt = j >> 2, Nt = j & 3;
                #pragma unroll
                for (int r = 0; r < 4; ++r) {
                    const int e = Mt * 16 + l4 * 4 + r;
                    if (e < 100) {
                        const unsigned short q = f2bf(eB[r]);
                        hh[e * 72 + Nt * 16 + l15] = q;
                        hT[(Nt * 16 + l15) * 136 + e] = q;
                    }
                }
            }
            const float* hsrc = layer ? out : hidden;
            for (int g = tid; g < 1600; g += 1024) {
                const int n = g >> 4, d0 = (g & 15) * 4;
                const float4 v = ld4(&hsrc[((size_t)b * N_ + n) * D_ + d0]);
                ec[n * 66 + d0 + 0] = v.x + sc_lds[d0 + 0];
                ec[n * 66 + d0 + 1] = v.y + sc_lds[d0 + 1];
                ec[n * 66 + d0 + 2] = v.z + sc_lds[d0 + 2];
                ec[n * 66 + d0 + 3] = v.w + sc_lds[d0 + 3];
            }
            prefill_S();
        }
        __syncthreads();
        score(3, true);             // S[n][e]
        __syncthreads();
        softmax_to_PT();            // PT[n][e]
        __syncthreads();
        // r = PT . edgeT
        f32x4 oA = { 0, 0, 0, 0 }, oB = { 0, 0, 0, 0 };
        mm_PT_hT(oA, oB);
        __syncthreads();
        // write out (+ restage r1 as next-layer h for L0)
        {
            {
                const int Mt = wv >> 2, Nt = wv & 3;
                #pragma unroll
                for (int r = 0; r < 4; ++r) {
                    const int n = Mt * 16 + l4 * 4 + r;
                    if (n < 100) {
                        const int idx = ((size_t)b * N_ + n) * D_ + Nt * 16 + l15;
                        if (layer == 0) {
                            out[idx] = oA[r];
                            const unsigned short q = f2bf(oA[r]);
                            hh[n * 72 + Nt * 16 + l15] = q;
                            hT[(Nt * 16 + l15) * 136 + n] = q;
                        } else {
                            out[idx] += oA[r];
                        }
                    }
                }
            }
            const int j = wv + 16;
            if (j < 28) {
                const int Mt = j >> 2, Nt = j & 3;
                #pragma unroll
                for (int r = 0; r < 4; ++r) {
                    const int n = Mt * 16 + l4 * 4 + r;
                    if (n < 100) {
                        const int idx = ((size_t)b * N_ + n) * D_ + Nt * 16 + l15;
                        if (layer == 0) {
                            out[idx] = oB[r];
                            const unsigned short q = f2bf(oB[r]);
                            hh[n * 72 + Nt * 16 + l15] = q;
                            hT[(Nt * 16 + l15) * 136 + n] = q;
                        } else {
                            out[idx] += oB[r];
                        }
                    }
                }
            }
        }
        __syncthreads();
    }
}

extern "C" void kernel_launch(void* const* d_in, const int* in_sizes, int n_in,
                              void* d_out, int out_size, void* d_ws, size_t ws_size,
                              hipStream_t stream) {
    const float* hidden = (const float*)d_in[0];
    const float* Hm     = (const float*)d_in[1];
    const float* s_c    = (const float*)d_in[2];
    const float* a10    = (const float*)d_in[3];
    const float* a11    = (const float*)d_in[4];
    const float* a12    = (const float*)d_in[5];
    const float* a20    = (const float*)d_in[6];
    const float* a21    = (const float*)d_in[7];
    const float* a22    = (const float*)d_in[8];
    float* out = (float*)d_out;

    k_mono<<<dim3(B_), 1024, 0, stream>>>(hidden, Hm, s_c,
                                          a10, a11, a12, a20, a21, a22, out);
}